// Round 10
// baseline (148.327 us; speedup 1.0000x reference)
//
#include <hip/hip_runtime.h>

// CenterLoss: loss = 0.5/B * (FF - 2*DOT + CC)
//   FF  = sum_i ||f_i||^2                     (fp32, exact, from pass kP)
//   DOT = sum_c S_c . newc_c                  (S_c from bf16 sorted copy)
//   CC  = sum_c count_c * ||newc_c||^2
//   newc_c = count_c>0 ? 0.5*centers_c + 0.5*S_c/count_c : centers_c
//
// R10: scatter-then-stream. Random-granule READS are capped ~1.7 TB/s on this
// chip (R4/R6/R7/R9: occupancy-null, L3-resident-null) -> eliminate them.
//   kP: stream feats (sequential 1KB wave-loads), FF in fp32, convert rows to
//       bf16 (512B) and scatter-WRITE to class-sorted positions (writes are
//       fire-and-forget; bytes halved vs fp32).
//   kR: stream the sorted bf16 copy sequentially; register segment-reduce;
//       class of a position via binary search over offsets; rare atomic
//       flushes into sums[C][D].
//   k_epi: DOT/CC from sums/counts/centers; last block emits loss.

#define DDIM 256
#define NHB 64            // histogram partial blocks
#define HPAD 1024

__device__ __forceinline__ unsigned short f2bf(float x) {
    unsigned u = __float_as_uint(x);
    unsigned r = (u + 0x7FFFu + ((u >> 16) & 1u)) >> 16;   // RNE
    return (unsigned short)r;
}
__device__ __forceinline__ float bf2f(unsigned short b) {
    return __uint_as_float(((unsigned)b) << 16);
}

// ws (ints): counts[1024] | offsets[1040] (sentinel at [C]) | cursor[1024]
//            | scalars[16] | hist_part[NHB*1024] | sums[C*256 f32]
//            | sorted bf16 rows: B * 64 ushort4 (67MB)
// scalars: [0]=FF [1]=DOT [2]=CC, ticket at slot 12

__global__ __launch_bounds__(256) void k1_hist(const int* __restrict__ labels,
                                               int* __restrict__ hist_part,
                                               float* __restrict__ sums,
                                               float* __restrict__ scal16,
                                               int B, int C) {
    __shared__ int h[1024];
    int b = blockIdx.x, t = threadIdx.x;
    for (int i = t; i < 1024; i += 256) h[i] = 0;
    __syncthreads();
    int per = (B + NHB - 1) / NHB;
    int base = b * per;
    int end = min(B, base + per);
    for (int i = base + t; i < end; i += 256) atomicAdd(&h[labels[i]], 1);
    __syncthreads();
    for (int i = t; i < 1024; i += 256) hist_part[b * HPAD + i] = h[i];
    // zero sums cooperatively across the NHB blocks
    int nf4 = C * (DDIM / 4);
    float4* s4 = (float4*)sums;
    float4 z = make_float4(0.f, 0.f, 0.f, 0.f);
    for (int i = b * 256 + t; i < nf4; i += NHB * 256) s4[i] = z;
    if (b == 0 && t < 16) scal16[t] = 0.f;
}

// Reduce NHB partials per class, Hillis-Steele scan -> counts/offsets/cursor.
__global__ __launch_bounds__(1024) void k2_scan(const int* __restrict__ hist_part,
                                                int* __restrict__ counts,
                                                int* __restrict__ offsets,
                                                int* __restrict__ cursor,
                                                int C, int B) {
    __shared__ int sc[1024];
    int t = threadIdx.x;
    int v = 0;
    for (int b = 0; b < NHB; ++b) v += hist_part[b * HPAD + t];
    sc[t] = v;
    __syncthreads();
    for (int off = 1; off < 1024; off <<= 1) {
        int add = (t >= off) ? sc[t - off] : 0;
        __syncthreads();
        sc[t] += add;
        __syncthreads();
    }
    if (t < C) {
        int e = sc[t] - v;
        counts[t] = v;
        offsets[t] = e;
        cursor[t]  = e;
    }
    if (t == C) offsets[C] = B;       // sentinel for binary search
}

// Scatter pass: wave owns 64 consecutive SOURCE rows (sequential 1KB reads).
// Each lane claims the sorted position for its own row (64 parallel cursor
// atomics per wave), then the wave writes each row as 512B bf16 to its slot.
__global__ __launch_bounds__(256) void kP_scatter(const float4* __restrict__ feats4,
                                                  const int* __restrict__ labels,
                                                  int* __restrict__ cursor,
                                                  ushort4* __restrict__ dstb,
                                                  float* __restrict__ scalars,
                                                  int B) {
    int t = threadIdx.x, wave = t >> 6, lane = t & 63;
    int g = blockIdx.x * 4 + wave;
    int start = g * 64;
    if (start >= B) return;

    int lbl = labels[start + lane];
    int pos = atomicAdd(&cursor[lbl], 1);     // sorted slot for row start+lane

    float ff = 0.f;

#define PROW(K, V) {                                                        \
        ff += V.x*V.x + V.y*V.y + V.z*V.z + V.w*V.w;                        \
        int q = __shfl(pos, (K));                                           \
        ushort4 o; o.x = f2bf(V.x); o.y = f2bf(V.y);                        \
        o.z = f2bf(V.z); o.w = f2bf(V.w);                                   \
        dstb[(size_t)q * 64 + lane] = o; }

    for (int i = 0; i < 64; i += 8) {
        int r = start + i;
        // 8 sequential 1KB wave-loads in flight
        float4 v0 = feats4[(size_t)(r + 0) * 64 + lane];
        float4 v1 = feats4[(size_t)(r + 1) * 64 + lane];
        float4 v2 = feats4[(size_t)(r + 2) * 64 + lane];
        float4 v3 = feats4[(size_t)(r + 3) * 64 + lane];
        float4 v4 = feats4[(size_t)(r + 4) * 64 + lane];
        float4 v5 = feats4[(size_t)(r + 5) * 64 + lane];
        float4 v6 = feats4[(size_t)(r + 6) * 64 + lane];
        float4 v7 = feats4[(size_t)(r + 7) * 64 + lane];
        PROW(i + 0, v0); PROW(i + 1, v1); PROW(i + 2, v2); PROW(i + 3, v3);
        PROW(i + 4, v4); PROW(i + 5, v5); PROW(i + 6, v6); PROW(i + 7, v7);
    }
#undef PROW

#pragma unroll
    for (int off = 32; off > 0; off >>= 1) ff += __shfl_xor(ff, off);
    if (lane == 0) atomicAdd(&scalars[0], ff);
}

// Reduce pass: wave owns 64 consecutive SORTED positions (sequential 512B
// reads). Class per position via 10-step binary search over offsets (L2-hot).
// Register accumulate; flush on class boundary (~1.5 per span).
__global__ __launch_bounds__(256) void kR_reduce(const ushort4* __restrict__ dstb,
                                                 const int* __restrict__ offsets,
                                                 float* __restrict__ sums,
                                                 int B, int C) {
    int t = threadIdx.x, wave = t >> 6, lane = t & 63;
    int g = blockIdx.x * 4 + wave;
    int start = g * 64;
    if (start >= B) return;

    // class of position start+lane: largest c with offsets[c] <= p
    int p = start + lane;
    int lo = 0, hi = C;
    while (hi - lo > 1) {
        int mid = (lo + hi) >> 1;
        if (offsets[mid] <= p) lo = mid; else hi = mid;
    }
    int lbl = lo;

    float4 acc = make_float4(0.f, 0.f, 0.f, 0.f);
    int cur = __shfl(lbl, 0);

#define FLUSH() do { float* bp = &sums[cur * DDIM + lane * 4];              \
        atomicAdd(bp + 0, acc.x); atomicAdd(bp + 1, acc.y);                 \
        atomicAdd(bp + 2, acc.z); atomicAdd(bp + 3, acc.w); } while (0)

#define ROWK(IDX, W) { int ck = __shfl(lbl, (IDX));                         \
        if (ck != cur) { FLUSH(); acc = make_float4(0.f,0.f,0.f,0.f); cur = ck; } \
        acc.x += W.x; acc.y += W.y; acc.z += W.z; acc.w += W.w; }

    for (int i = 0; i < 64; i += 8) {
        size_t r = (size_t)(start + i) * 64 + lane;
        ushort4 u0 = dstb[r];       ushort4 u1 = dstb[r + 64];
        ushort4 u2 = dstb[r + 128]; ushort4 u3 = dstb[r + 192];
        ushort4 u4 = dstb[r + 256]; ushort4 u5 = dstb[r + 320];
        ushort4 u6 = dstb[r + 384]; ushort4 u7 = dstb[r + 448];
        float4 w0 = make_float4(bf2f(u0.x), bf2f(u0.y), bf2f(u0.z), bf2f(u0.w));
        float4 w1 = make_float4(bf2f(u1.x), bf2f(u1.y), bf2f(u1.z), bf2f(u1.w));
        float4 w2 = make_float4(bf2f(u2.x), bf2f(u2.y), bf2f(u2.z), bf2f(u2.w));
        float4 w3 = make_float4(bf2f(u3.x), bf2f(u3.y), bf2f(u3.z), bf2f(u3.w));
        float4 w4 = make_float4(bf2f(u4.x), bf2f(u4.y), bf2f(u4.z), bf2f(u4.w));
        float4 w5 = make_float4(bf2f(u5.x), bf2f(u5.y), bf2f(u5.z), bf2f(u5.w));
        float4 w6 = make_float4(bf2f(u6.x), bf2f(u6.y), bf2f(u6.z), bf2f(u6.w));
        float4 w7 = make_float4(bf2f(u7.x), bf2f(u7.y), bf2f(u7.z), bf2f(u7.w));
        int c0 = __shfl(lbl, i), c7 = __shfl(lbl, i + 7);
        if (c0 == cur && c7 == cur) {   // labels nondecreasing -> whole group
            acc.x += w0.x + w1.x + w2.x + w3.x + w4.x + w5.x + w6.x + w7.x;
            acc.y += w0.y + w1.y + w2.y + w3.y + w4.y + w5.y + w6.y + w7.y;
            acc.z += w0.z + w1.z + w2.z + w3.z + w4.z + w5.z + w6.z + w7.z;
            acc.w += w0.w + w1.w + w2.w + w3.w + w4.w + w5.w + w6.w + w7.w;
        } else {
            ROWK(i + 0, w0); ROWK(i + 1, w1); ROWK(i + 2, w2); ROWK(i + 3, w3);
            ROWK(i + 4, w4); ROWK(i + 5, w5); ROWK(i + 6, w6); ROWK(i + 7, w7);
        }
    }
    FLUSH();
#undef ROWK
#undef FLUSH
}

// One 64-thread block per class: DOT/CC from sums/counts/centers; last -> loss.
__global__ __launch_bounds__(64) void k_epi(const float* __restrict__ sums,
                                            const float* __restrict__ centers,
                                            const int* __restrict__ counts,
                                            float* __restrict__ scalars,
                                            int* __restrict__ ticket,
                                            float* __restrict__ out,
                                            int C, float invB) {
    int c = blockIdx.x, lane = threadIdx.x;
    float4 s  = *(const float4*)&sums[c * DDIM + lane * 4];
    float4 co = *(const float4*)&centers[c * DDIM + lane * 4];
    int n = counts[c];
    float inv = (n > 0) ? 0.5f / (float)n : 0.f;
    float4 nc;
    nc.x = 0.5f * co.x + s.x * inv;   // n==0: s==0 -> dotv=ccv=0 regardless
    nc.y = 0.5f * co.y + s.y * inv;
    nc.z = 0.5f * co.z + s.z * inv;
    nc.w = 0.5f * co.w + s.w * inv;
    float dotv = nc.x * s.x + nc.y * s.y + nc.z * s.z + nc.w * s.w;
    float ccv  = (nc.x*nc.x + nc.y*nc.y + nc.z*nc.z + nc.w*nc.w) * (float)n;

#pragma unroll
    for (int off = 32; off > 0; off >>= 1) {
        dotv += __shfl_down(dotv, off);
        ccv  += __shfl_down(ccv, off);
    }
    if (lane == 0) {
        atomicAdd(&scalars[1], dotv);
        atomicAdd(&scalars[2], ccv);
        __threadfence();
        int old = atomicAdd(ticket, 1);
        if (old == C - 1) {
            __threadfence();
            float A  = atomicAdd(&scalars[0], 0.f);
            float Bv = atomicAdd(&scalars[1], 0.f);
            float E  = atomicAdd(&scalars[2], 0.f);
            out[0] = 0.5f * invB * (A - 2.f * Bv + E);
        }
    }
}

extern "C" void kernel_launch(void* const* d_in, const int* in_sizes, int n_in,
                              void* d_out, int out_size, void* d_ws, size_t ws_size,
                              hipStream_t stream) {
    const float* feats   = (const float*)d_in[0];
    const float* centers = (const float*)d_in[1];
    const int*   labels  = (const int*)d_in[2];

    int B = in_sizes[2];              // 131072
    int Dv = in_sizes[0] / B;         // 256 (kernel assumes 256)
    int C = in_sizes[1] / Dv;         // 1000 (<=1023 assumed)
    (void)Dv; (void)n_in; (void)ws_size; (void)out_size;

    int* W = (int*)d_ws;
    int* counts    = W;                          // 1024
    int* offsets   = W + 1024;                   // 1040 (sentinel at [C])
    int* cursor    = W + 1024 + 1040;            // 1024
    float* scalars = (float*)(W + 3088);         // 16: [0]FF [1]DOT [2]CC
    int* ticket    = W + 3088 + 12;              // scalars slot 12
    int* hist_part = W + 3088 + 16;              // NHB*1024
    float* sums    = (float*)(hist_part + NHB * HPAD);  // C*256 f32
    ushort4* dstb  = (ushort4*)(sums + C * DDIM);       // B*64 ushort4 (67MB)

    k1_hist<<<NHB, 256, 0, stream>>>(labels, hist_part, sums, scalars, B, C);
    k2_scan<<<1, 1024, 0, stream>>>(hist_part, counts, offsets, cursor, C, B);
    int gblocks = (B + 255) / 256;               // 4 waves x 64 rows per block
    kP_scatter<<<gblocks, 256, 0, stream>>>((const float4*)feats, labels,
                                            cursor, dstb, scalars, B);
    kR_reduce<<<gblocks, 256, 0, stream>>>(dstb, offsets, sums, B, C);
    k_epi<<<C, 64, 0, stream>>>(sums, centers, counts, scalars, ticket,
                                (float*)d_out, C, 1.0f / (float)B);
}

// Round 11
// 132.956 us; speedup vs baseline: 1.1156x; 1.1156x over previous
//
#include <hip/hip_runtime.h>
#include <stdint.h>

// CenterLoss: loss = 0.5/B * (FF - 2*DOT + CC)
//   FF  = sum_i ||f_i||^2
//   DOT = sum_c S_c . newc_c           (S_c = sum of feats rows with label c)
//   CC  = sum_c count_c * ||newc_c||^2
//   newc_c = count_c>0 ? 0.5*centers_c + 0.5*S_c/count_c : centers_c
//
// R11: span-gather through global_load_lds (direct-to-LDS DMA). Random-granule
// loads through the VGPR path cap at ~1.6 TB/s regardless of occupancy/unroll/
// L3-residency (R4-R10). This variant keeps 16 KB of row-DMA in flight per
// wave with no register return path: issue 16x global_load_lds (1 KB row
// each), one vmcnt(0) drain, consume from LDS conflict-free. Sort machinery:
// hist -> scan -> scatter of packed int2{row,label} -> span gather -> epilogue.

#define DDIM 256
#define NHB 16
#define HPAD 1024
#define SLOTS 16

typedef __attribute__((address_space(1))) uint32_t gu32;
typedef __attribute__((address_space(3))) uint32_t lu32;

__device__ __forceinline__ void gload16(const float* g, float* l) {
    // per-lane global src (16B each); wave-uniform LDS base, HW adds lane*16
    __builtin_amdgcn_global_load_lds((const gu32*)g, (lu32*)l, 16, 0, 0);
}

// ws (ints): counts[1024] | offsets[1024] | cursor[1024] | scalars[16]
//            | hist_part[NHB*1024] | meta int2[B] | sums[C*256 f32]
// scalars: [0]=FF [1]=DOT [2]=CC, ticket at slot 12

__global__ __launch_bounds__(256) void k1_hist(const int* __restrict__ labels,
                                               int* __restrict__ hist_part,
                                               float* __restrict__ scal16,
                                               int B, int C) {
    __shared__ int h[1024];
    int b = blockIdx.x, t = threadIdx.x;
    for (int i = t; i < 1024; i += 256) h[i] = 0;
    __syncthreads();
    int per = (B + NHB - 1) / NHB;
    int base = b * per;
    int end = min(B, base + per);
    for (int i = base + t; i < end; i += 256) atomicAdd(&h[labels[i]], 1);
    __syncthreads();
    for (int i = t; i < 1024; i += 256) hist_part[b * HPAD + i] = h[i];
    if (b == 0 && t < 16) scal16[t] = 0.f;
}

// Reduce NHB partials per class, Hillis-Steele scan -> counts/offsets/cursor.
__global__ __launch_bounds__(1024) void k2_scan(const int* __restrict__ hist_part,
                                                int* __restrict__ counts,
                                                int* __restrict__ offsets,
                                                int* __restrict__ cursor, int C) {
    __shared__ int sc[1024];
    int t = threadIdx.x;
    int v = 0;
#pragma unroll
    for (int b = 0; b < NHB; ++b) v += hist_part[b * HPAD + t];
    sc[t] = v;
    __syncthreads();
    for (int off = 1; off < 1024; off <<= 1) {
        int add = (t >= off) ? sc[t - off] : 0;
        __syncthreads();
        sc[t] += add;
        __syncthreads();
    }
    if (t < C) {
        int e = sc[t] - v;
        counts[t] = v;
        offsets[t] = e;
        cursor[t]  = e;
    }
}

// Scatter packed {row,label}; also zero sums with this 512-block grid.
__global__ __launch_bounds__(256) void k3_scatter(const int* __restrict__ labels,
                                                  int* __restrict__ cursor,
                                                  int2* __restrict__ meta,
                                                  float4* __restrict__ sums4,
                                                  int B, int nf4) {
    int stride = gridDim.x * 256;
    int tid = blockIdx.x * 256 + threadIdx.x;
    float4 z = make_float4(0.f, 0.f, 0.f, 0.f);
    for (int i = tid; i < nf4; i += stride) sums4[i] = z;
    for (int i = tid; i < B; i += stride) {
        int c = labels[i];
        int pos = atomicAdd(&cursor[c], 1);
        meta[pos] = make_int2(i, c);
    }
}

// Span gather via global_load_lds: wave g owns sorted positions [64g,64g+64).
// Per batch of 16 rows: issue 16 row-DMAs (16 KB in flight), vmcnt(0) drain,
// consume from LDS (lane reads its own 16B -> conflict-free). Class-run
// register accumulation; flush on boundary (~1.5/span) via global atomics.
__global__ __launch_bounds__(256) void k4_span(const float* __restrict__ feats,
                                               const int2* __restrict__ meta,
                                               float* __restrict__ sums,
                                               float* __restrict__ scalars, int B) {
    __shared__ float rows_lds[4 * SLOTS * DDIM];   // 4 waves x 16 rows x 1KB = 64KB
    int t = threadIdx.x, wave = t >> 6, lane = t & 63;
    int g = blockIdx.x * 4 + wave;
    int start = g * 64;
    if (start >= B) return;
    int n = min(64, B - start);

    int2 me = meta[start + ((lane < n) ? lane : (n - 1))];
    int ridx = me.x, lbl = me.y;

    float* myslots = &rows_lds[(wave * SLOTS) * DDIM];

    float4 acc = make_float4(0.f, 0.f, 0.f, 0.f);
    float ff = 0.f;
    int cur = __shfl(lbl, 0);

#define FLUSH() do { float* bp = &sums[cur * DDIM + lane * 4];              \
        atomicAdd(bp + 0, acc.x); atomicAdd(bp + 1, acc.y);                 \
        atomicAdd(bp + 2, acc.z); atomicAdd(bp + 3, acc.w); } while (0)

    if (n == 64) {
        for (int b = 0; b < 64; b += SLOTS) {
            // issue 16 direct-to-LDS row loads (no VGPR return path)
#pragma unroll
            for (int j = 0; j < SLOTS; ++j) {
                int r = __shfl(ridx, b + j);
                gload16(feats + (size_t)r * DDIM + lane * 4, myslots + j * DDIM);
            }
            asm volatile("s_waitcnt vmcnt(0)" ::: "memory");
            __builtin_amdgcn_sched_barrier(0);

            int cA = __shfl(lbl, b), cZ = __shfl(lbl, b + SLOTS - 1);
            if (cA == cur && cZ == cur) {   // labels nondecreasing -> whole batch
#pragma unroll
                for (int j = 0; j < SLOTS; ++j) {
                    float4 v = *(const float4*)(myslots + j * DDIM + lane * 4);
                    acc.x += v.x; acc.y += v.y; acc.z += v.z; acc.w += v.w;
                    ff += v.x*v.x + v.y*v.y + v.z*v.z + v.w*v.w;
                }
            } else {
#pragma unroll
                for (int j = 0; j < SLOTS; ++j) {
                    float4 v = *(const float4*)(myslots + j * DDIM + lane * 4);
                    ff += v.x*v.x + v.y*v.y + v.z*v.z + v.w*v.w;
                    int ck = __shfl(lbl, b + j);
                    if (ck != cur) {
                        FLUSH();
                        acc = make_float4(0.f, 0.f, 0.f, 0.f);
                        cur = ck;
                    }
                    acc.x += v.x; acc.y += v.y; acc.z += v.z; acc.w += v.w;
                }
            }
        }
    } else {
        const float4* f4 = (const float4*)feats;
        for (int i = 0; i < n; ++i) {
            int r = __shfl(ridx, i);
            float4 v = f4[(size_t)r * 64 + lane];
            ff += v.x*v.x + v.y*v.y + v.z*v.z + v.w*v.w;
            int ck = __shfl(lbl, i);
            if (ck != cur) {
                FLUSH();
                acc = make_float4(0.f, 0.f, 0.f, 0.f);
                cur = ck;
            }
            acc.x += v.x; acc.y += v.y; acc.z += v.z; acc.w += v.w;
        }
    }
    FLUSH();
#undef FLUSH

#pragma unroll
    for (int off = 32; off > 0; off >>= 1) ff += __shfl_xor(ff, off);
    if (lane == 0) atomicAdd(&scalars[0], ff);
}

// One 64-thread block per class: DOT/CC from sums/counts/centers; last -> loss.
__global__ __launch_bounds__(64) void k_epi(const float* __restrict__ sums,
                                            const float* __restrict__ centers,
                                            const int* __restrict__ counts,
                                            float* __restrict__ scalars,
                                            int* __restrict__ ticket,
                                            float* __restrict__ out,
                                            int C, float invB) {
    int c = blockIdx.x, lane = threadIdx.x;
    float4 s  = *(const float4*)&sums[c * DDIM + lane * 4];
    float4 co = *(const float4*)&centers[c * DDIM + lane * 4];
    int n = counts[c];
    float inv = (n > 0) ? 0.5f / (float)n : 0.f;
    float4 nc;
    nc.x = 0.5f * co.x + s.x * inv;   // n==0: s==0 -> dotv=ccv=0 regardless
    nc.y = 0.5f * co.y + s.y * inv;
    nc.z = 0.5f * co.z + s.z * inv;
    nc.w = 0.5f * co.w + s.w * inv;
    float dotv = nc.x * s.x + nc.y * s.y + nc.z * s.z + nc.w * s.w;
    float ccv  = (nc.x*nc.x + nc.y*nc.y + nc.z*nc.z + nc.w*nc.w) * (float)n;

#pragma unroll
    for (int off = 32; off > 0; off >>= 1) {
        dotv += __shfl_down(dotv, off);
        ccv  += __shfl_down(ccv, off);
    }
    if (lane == 0) {
        atomicAdd(&scalars[1], dotv);
        atomicAdd(&scalars[2], ccv);
        __threadfence();
        int old = atomicAdd(ticket, 1);
        if (old == C - 1) {
            __threadfence();
            float A  = atomicAdd(&scalars[0], 0.f);
            float Bv = atomicAdd(&scalars[1], 0.f);
            float E  = atomicAdd(&scalars[2], 0.f);
            out[0] = 0.5f * invB * (A - 2.f * Bv + E);
        }
    }
}

extern "C" void kernel_launch(void* const* d_in, const int* in_sizes, int n_in,
                              void* d_out, int out_size, void* d_ws, size_t ws_size,
                              hipStream_t stream) {
    const float* feats   = (const float*)d_in[0];
    const float* centers = (const float*)d_in[1];
    const int*   labels  = (const int*)d_in[2];

    int B = in_sizes[2];              // 131072
    int Dv = in_sizes[0] / B;         // 256 (kernel assumes 256)
    int C = in_sizes[1] / Dv;         // 1000 (<=1024 assumed)
    (void)Dv; (void)n_in; (void)ws_size; (void)out_size;

    int* W = (int*)d_ws;
    int* counts    = W;                          // 1024
    int* offsets   = W + 1024;                   // 1024
    int* cursor    = W + 2048;                   // 1024
    float* scalars = (float*)(W + 3072);         // 16: [0]FF [1]DOT [2]CC
    int* ticket    = W + 3072 + 12;              // scalars slot 12
    int* hist_part = W + 3072 + 16;              // NHB*1024
    int2* meta     = (int2*)(hist_part + NHB * HPAD);   // B (8B aligned)
    float* sums    = (float*)(meta + B);                 // C*256 f32

    k1_hist<<<NHB, 256, 0, stream>>>(labels, hist_part, scalars, B, C);
    k2_scan<<<1, 1024, 0, stream>>>(hist_part, counts, offsets, cursor, C);
    int sblocks = (B + 255) / 256;
    if (sblocks > 512) sblocks = 512;
    k3_scatter<<<sblocks, 256, 0, stream>>>(labels, cursor, meta,
                                            (float4*)sums, B, C * DDIM / 4);
    int gblocks = (B + 255) / 256;               // 4 waves x 64 rows per block
    k4_span<<<gblocks, 256, 0, stream>>>(feats, meta, sums, scalars, B);
    k_epi<<<C, 64, 0, stream>>>(sums, centers, counts, scalars, ticket,
                                (float*)d_out, C, 1.0f / (float)B);
}